// Round 6
// baseline (320.455 us; speedup 1.0000x reference)
//
#include <hip/hip_runtime.h>
#include <hip/hip_bf16.h>
#include <math.h>

typedef __bf16 bf16_t;
typedef bf16_t bf16x8 __attribute__((ext_vector_type(8)));
typedef bf16_t bf16x4 __attribute__((ext_vector_type(4)));
typedef float  f32x4  __attribute__((ext_vector_type(4)));
typedef float  vf4    __attribute__((ext_vector_type(4)));

#define HH 2048
#define BB 32
#define TT 4
#define FF 19
#define NBLK 256
#define NTHR 512

// ---- dynamic LDS layout (bytes) ----
#define LDS_WHH   0         // bf16[32][2048] swizzled : 131072
#define LDS_X     131072    // float[128][20]          : 10240
#define LDS_WIH0  141312    // float[32][20]           : 2560
#define LDS_B0    143872    // float[32]               : 128
#define LDS_B1    144000    // float[32]               : 128
#define LDS_GP    144128    // float[2][32][33]        : 8448
#define LDS_TOTAL 152608

// ---- workspace layout (bytes) ----
// slots 0..6 x 1024 B barrier headers; broadcast lines at 8192 (8 x 128 B);
// final-reduce accum/count at 9216/9600. All zeroed by memset each launch.
#define WS_BCAST  8192
#define WS_FACC   9216      // float[32]
#define WS_FCNT   9600      // unsigned[32]
#define BAR_BYTES 12288
#define WS_H0     16384     // bf16 [T*B][2048] : 524288
#define WS_H1     540672    // bf16 [T*B][2048] : 524288
#define WS_G1     1064960   // f32 [128][256][32] : 4194304

__device__ __forceinline__ float sigm(float x) { return 1.0f / (1.0f + expf(-x)); }

// ---- fence-free two-level grid barrier, low-contention broadcast release ----
// (R5-validated). No __threadfence: h-stores are write-through agent atomics
// drained by the vmcnt(0) __syncthreads emits; h regions are written once and
// read only post-barrier, so no XCD cache holds a stale pre-barrier copy.
__device__ __forceinline__ void gbar_arrive(char* barbase, int slot, int blk) {
    __syncthreads();
    if (threadIdx.x == 0) {
        unsigned* base = (unsigned*)(barbase + slot * 1024);
        if (__hip_atomic_fetch_add(base + (blk & 7) * 16, 1u, __ATOMIC_RELAXED, __HIP_MEMORY_SCOPE_AGENT) == 31u)
            if (__hip_atomic_fetch_add(base + 128, 1u, __ATOMIC_RELAXED, __HIP_MEMORY_SCOPE_AGENT) == 7u) {
                unsigned* bc = (unsigned*)(barbase + WS_BCAST);
                #pragma unroll
                for (int g = 0; g < 8; ++g)
                    __hip_atomic_store(bc + g * 32, (unsigned)(slot + 1), __ATOMIC_RELAXED, __HIP_MEMORY_SCOPE_AGENT);
            }
    }
}
__device__ __forceinline__ void gbar_wait(char* barbase, int slot, int blk) {
    if (threadIdx.x == 0) {
        unsigned* line = (unsigned*)(barbase + WS_BCAST) + (blk & 7) * 32;
        while (__hip_atomic_load(line, __ATOMIC_RELAXED, __HIP_MEMORY_SCOPE_AGENT) < (unsigned)(slot + 1))
            __builtin_amdgcn_s_sleep(1);
    }
    __syncthreads();
}

// Direct staging: 32 gate-rows x 2048 f32 -> bf16 LDS, swizzle byte^=((row&7)<<4).
__device__ __forceinline__ void load_w_lds(char* smem, const float* __restrict__ w, int blk, int tid) {
    char* dst = smem + LDS_WHH;
    #pragma unroll 1
    for (int base = 0; base < 32; base += 8) {
        vf4 v[8];
        #pragma unroll
        for (int j = 0; j < 8; ++j) {
            int row = base + j;
            int gr = (row >> 3) * 2048 + blk * 8 + (row & 7);
            v[j] = *reinterpret_cast<const vf4*>(w + (size_t)gr * 2048 + tid * 4);
        }
        #pragma unroll
        for (int j = 0; j < 8; ++j) {
            int row = base + j;
            bf16x4 bv;
            bv[0] = (bf16_t)v[j][0]; bv[1] = (bf16_t)v[j][1];
            bv[2] = (bf16_t)v[j][2]; bv[3] = (bf16_t)v[j][3];
            unsigned byte = (unsigned)(row * 4096) + (((unsigned)(tid * 8)) ^ (((unsigned)(row & 7)) << 4));
            *reinterpret_cast<bf16x4*>(dst + byte) = bv;
        }
    }
}

// Write the 32-row register payload (each thread's 4-f32-wide column slice per
// row, bf16) into the swizzled LDS weight tile. pay[] indices are all
// compile-time (full unroll) so the array stays in VGPRs (rule #20).
__device__ __forceinline__ void ds_write_pay(char* smem, const bf16x4* pay, int tid) {
    char* dst = smem + LDS_WHH;
    #pragma unroll
    for (int row = 0; row < 32; ++row) {
        unsigned byte = (unsigned)(row * 4096) + (((unsigned)(tid * 8)) ^ (((unsigned)(row & 7)) << 4));
        *reinterpret_cast<bf16x4*>(dst + byte) = pay[row];
    }
}

// gates(32x32) = h_prev(32x2048 bf16 global) @ w_lds.T ; 8 waves =
// quadrant(2b) x K-half(1b); partials -> gparts[2][32][33].
__device__ __forceinline__ void step_gemm(const __hip_bfloat16* __restrict__ hprev,
                                          const char* smem, float* gparts,
                                          int lane, int wv) {
    const int q  = wv >> 1;
    const int kh = wv & 1;
    const int mt = q >> 1, nt = q & 1;
    const int r = lane & 15, g4 = lane >> 4;
    f32x4 acc0 = {0.f,0.f,0.f,0.f}, acc1 = {0.f,0.f,0.f,0.f};
    const char* bbase = smem + LDS_WHH;
    const int n = nt * 16 + r;
    const unsigned brow = (unsigned)(n * 4096);
    const unsigned bsw = ((unsigned)(n & 7)) << 4;
    const __hip_bfloat16* aptr = hprev + (mt * 16 + r) * 2048 + g4 * 8;
    const int k0 = kh * 32;
    #pragma unroll
    for (int ks = 0; ks < 32; ks += 2) {
        int ka = k0 + ks, kb = k0 + ks + 1;
        bf16x8 a0 = *reinterpret_cast<const bf16x8*>(aptr + ka * 32);
        bf16x8 b0 = *reinterpret_cast<const bf16x8*>(bbase + brow + (((unsigned)(ka * 64 + g4 * 16)) ^ bsw));
        acc0 = __builtin_amdgcn_mfma_f32_16x16x32_bf16(a0, b0, acc0, 0, 0, 0);
        bf16x8 a1 = *reinterpret_cast<const bf16x8*>(aptr + kb * 32);
        bf16x8 b1 = *reinterpret_cast<const bf16x8*>(bbase + brow + (((unsigned)(kb * 64 + g4 * 16)) ^ bsw));
        acc1 = __builtin_amdgcn_mfma_f32_16x16x32_bf16(a1, b1, acc1, 0, 0, 0);
    }
    f32x4 s = acc0 + acc1;
    #pragma unroll
    for (int r2 = 0; r2 < 4; ++r2)  // D map: col=lane&15, row=(lane>>4)*4+reg
        gparts[(kh * 32 + mt * 16 + g4 * 4 + r2) * 33 + nt * 16 + r] = s[r2];
}

// write-through agent-scope bf16 store
__device__ __forceinline__ void store_h(__hip_bfloat16* p, float x) {
    __hip_bfloat16 hv = __float2bfloat16(x);
    unsigned short bits = *reinterpret_cast<unsigned short*>(&hv);
    __hip_atomic_store((unsigned short*)p, bits, __ATOMIC_RELAXED, __HIP_MEMORY_SCOPE_AGENT);
}

__global__ __launch_bounds__(NTHR, 2) void fused_lstm(
    const float* __restrict__ state, const float* __restrict__ action,
    const float* __restrict__ conv_w, const float* __restrict__ conv_b,
    const float* __restrict__ w_ih0, const float* __restrict__ w_hh0,
    const float* __restrict__ b_ih0, const float* __restrict__ b_hh0,
    const float* __restrict__ w_ih1, const float* __restrict__ w_hh1,
    const float* __restrict__ b_ih1, const float* __restrict__ b_hh1,
    const float* __restrict__ lin_w, const float* __restrict__ lin_b,
    float* __restrict__ out, char* __restrict__ ws)
{
    extern __shared__ char smem[];
    float* x_lds    = (float*)(smem + LDS_X);
    float* wih0_lds = (float*)(smem + LDS_WIH0);
    float* b0_lds   = (float*)(smem + LDS_B0);
    float* b1_lds   = (float*)(smem + LDS_B1);
    float* gparts   = (float*)(smem + LDS_GP);

    const int tid  = threadIdx.x;
    const int blk  = blockIdx.x;
    const int lane = tid & 63;
    const int wv   = tid >> 6;
    const int m    = tid >> 3;   // (tid<256) batch row owned in gate phase
    const int u    = tid & 7;    // (tid<256) local hidden unit owned

    __hip_bfloat16* h0_ws = (__hip_bfloat16*)(ws + WS_H0);
    __hip_bfloat16* h1_ws = (__hip_bfloat16*)(ws + WS_H1);
    float*          g1    = (float*)(ws + WS_G1);
    float*          facc  = (float*)(ws + WS_FACC);
    unsigned*       fcnt  = (unsigned*)(ws + WS_FCNT);

    bf16x4 pay[32];   // background weight payload (statically indexed only)

    // ---------- prep ----------
    float lw0 = 0.f, lw1 = 0.f, lw2 = 0.f, lw3 = 0.f, linb = 0.f;
    {
        float cw = conv_w[0], cb = conv_b[0];
        for (int i = tid; i < TT * BB * FF; i += NTHR) {
            int f = i % FF; int tb = i / FF; int t = tb >> 5; int mm = tb & 31;
            float v = (f < 15) ? state[(mm * TT + t) * 15 + f] : action[(mm * TT + t) * 4 + (f - 15)];
            x_lds[tb * 20 + f] = tanhf(cw * v + cb);
        }
        for (int i = tid; i < 32 * FF; i += NTHR) {
            int n = i / FF; int f = i % FF;
            int gr = (n >> 3) * 2048 + blk * 8 + (n & 7);
            wih0_lds[n * 20 + f] = w_ih0[(size_t)gr * FF + f];
        }
        if (tid < 32) {
            int gr = (tid >> 3) * 2048 + blk * 8 + (tid & 7);
            b0_lds[tid] = b_ih0[gr] + b_hh0[gr];
        }
        if (tid < 256) {
            int col = blk * 8 + u;
            lw0 = lin_w[col]; lw1 = lin_w[2048 + col];
            lw2 = lin_w[4096 + col]; lw3 = lin_w[6144 + col];
            linb = lin_b[0];
        }
    }
    __syncthreads();

    // ---------- layer 0, t=0 ----------
    float c0 = 0.f;
    if (tid < 256) {
        float gv[4];
        #pragma unroll
        for (int gate = 0; gate < 4; ++gate) {
            int n = gate * 8 + u;
            float a = b0_lds[n];
            const float* xr = &x_lds[m * 20];
            const float* wr = &wih0_lds[n * 20];
            #pragma unroll
            for (int f = 0; f < FF; ++f) a += xr[f] * wr[f];
            gv[gate] = a;
        }
        float ig = sigm(gv[0]), fg = sigm(gv[1]), g2 = tanhf(gv[2]), og = sigm(gv[3]);
        c0 = fg * c0 + ig * g2;
        store_h(h0_ws + (size_t)m * 2048 + blk * 8 + u, og * tanhf(c0));
    }
    gbar_arrive(ws, 0, blk);
    load_w_lds(smem, w_hh0, blk, tid);   // w_hh0 -> LDS (critical, unavoidable)
    gbar_wait(ws, 0, blk);

    // ---------- layer 0, t=1..3 (+ background w_ih1 -> pay regs) ----------
    #pragma unroll
    for (int t = 1; t < TT; ++t) {
        step_gemm(h0_ws + (size_t)(t - 1) * BB * HH, smem, gparts, lane, wv);
        __syncthreads();
        if (tid < 256) {
            float gv[4];
            #pragma unroll
            for (int gate = 0; gate < 4; ++gate) {
                int n = gate * 8 + u;
                float a = gparts[m * 33 + n] + gparts[(32 + m) * 33 + n] + b0_lds[n];
                const float* xr = &x_lds[(t * 32 + m) * 20];
                const float* wr = &wih0_lds[n * 20];
                #pragma unroll
                for (int f = 0; f < FF; ++f) a += xr[f] * wr[f];
                gv[gate] = a;
            }
            float ig = sigm(gv[0]), fg = sigm(gv[1]), g2 = tanhf(gv[2]), og = sigm(gv[3]);
            c0 = fg * c0 + ig * g2;
            store_h(h0_ws + (size_t)(t * 32 + m) * 2048 + blk * 8 + u, og * tanhf(c0));
        }
        gbar_arrive(ws, t, blk);
        {   // background w_ih1 chunk into payload regs (constant bounds per t)
            const int r0 = (t == 1) ? 0 : (t == 2) ? 10 : 21;
            const int r1 = (t == 1) ? 10 : (t == 2) ? 21 : 32;
            #pragma unroll
            for (int row = 0; row < 32; ++row) {
                if (row >= r0 && row < r1) {
                    int gr = (row >> 3) * 2048 + blk * 8 + (row & 7);
                    vf4 v = *reinterpret_cast<const vf4*>(w_ih1 + (size_t)gr * 2048 + tid * 4);
                    bf16x4 bv;
                    bv[0] = (bf16_t)v[0]; bv[1] = (bf16_t)v[1];
                    bv[2] = (bf16_t)v[2]; bv[3] = (bf16_t)v[3];
                    pay[row] = bv;
                }
            }
        }
        if (t == 3) {
            ds_write_pay(smem, pay, tid);   // w_ih1 -> LDS (w_hh0 is dead)
            if (tid < 32) {
                int gr = (tid >> 3) * 2048 + blk * 8 + (tid & 7);
                b1_lds[tid] = b_ih1[gr] + b_hh1[gr];
            }
        }
        gbar_wait(ws, t, blk);
    }

    // ---------- layer-1 input GEMM (w_ih1 from LDS) + background w_hh1 -> pay ----------
    {
        const int r = lane & 15, g4 = lane >> 4;
        const char* bbase = smem + LDS_WHH;
        const unsigned bsw0 = ((unsigned)(r & 7)) << 4;   // rows r and 16+r share (row&7)
        const int mt = wv;                                 // 8 waves -> 8 m-tiles of 16
        f32x4 acc0 = {0.f,0.f,0.f,0.f}, acc1 = {0.f,0.f,0.f,0.f};
        const __hip_bfloat16* aptr = h0_ws + (size_t)(mt * 16 + r) * 2048 + g4 * 8;
        #pragma unroll
        for (int c = 0; c < 4; ++c) {
            // issue+convert w_hh1 batch c (8 rows) into payload regs
            #pragma unroll
            for (int j = 0; j < 8; ++j) {
                int row = c * 8 + j;
                int gr = (row >> 3) * 2048 + blk * 8 + (row & 7);
                vf4 v = *reinterpret_cast<const vf4*>(w_hh1 + (size_t)gr * 2048 + tid * 4);
                bf16x4 bv;
                bv[0] = (bf16_t)v[0]; bv[1] = (bf16_t)v[1];
                bv[2] = (bf16_t)v[2]; bv[3] = (bf16_t)v[3];
                pay[row] = bv;
            }
            // g1 K-chunk (16 of 64 ks)
            #pragma unroll
            for (int kk = 0; kk < 16; ++kk) {
                int ks = c * 16 + kk;
                bf16x8 a  = *reinterpret_cast<const bf16x8*>(aptr + ks * 32);
                bf16x8 b0 = *reinterpret_cast<const bf16x8*>(bbase + (unsigned)(r * 4096)        + (((unsigned)(ks * 64 + g4 * 16)) ^ bsw0));
                bf16x8 b1 = *reinterpret_cast<const bf16x8*>(bbase + (unsigned)((16 + r) * 4096) + (((unsigned)(ks * 64 + g4 * 16)) ^ bsw0));
                acc0 = __builtin_amdgcn_mfma_f32_16x16x32_bf16(a, b0, acc0, 0, 0, 0);
                acc1 = __builtin_amdgcn_mfma_f32_16x16x32_bf16(a, b1, acc1, 0, 0, 0);
            }
        }
        #pragma unroll
        for (int r2 = 0; r2 < 4; ++r2) {
            int tb = mt * 16 + g4 * 4 + r2;
            g1[((size_t)tb * 256 + blk) * 32 + r]      = acc0[r2] + b1_lds[r];      // block-private
            g1[((size_t)tb * 256 + blk) * 32 + 16 + r] = acc1[r2] + b1_lds[16 + r];
        }
    }
    __syncthreads();   // g1 stores drained + all LDS w_ih1 reads complete

    // ---------- layer 1, t=0 ----------
    float c1 = 0.f, fsum = 0.f;
    if (tid < 256) {
        float gv[4];
        #pragma unroll
        for (int gate = 0; gate < 4; ++gate) {
            int n = gate * 8 + u;
            gv[gate] = g1[((size_t)m * 256 + blk) * 32 + n];
        }
        float ig = sigm(gv[0]), fg = sigm(gv[1]), g2 = tanhf(gv[2]), og = sigm(gv[3]);
        c1 = fg * c1 + ig * g2;
        float hval = og * tanhf(c1);
        fsum += hval * lw0;
        store_h(h1_ws + (size_t)m * 2048 + blk * 8 + u, hval);
    }
    gbar_arrive(ws, 4, blk);
    ds_write_pay(smem, pay, tid);   // w_hh1 -> LDS (after arrive's syncthreads)
    gbar_wait(ws, 4, blk);

    // ---------- layer 1, t=1..3 ----------
    #pragma unroll
    for (int t = 1; t < TT; ++t) {
        step_gemm(h1_ws + (size_t)(t - 1) * BB * HH, smem, gparts, lane, wv);
        __syncthreads();
        if (tid < 256) {
            float gv[4];
            #pragma unroll
            for (int gate = 0; gate < 4; ++gate) {
                int n = gate * 8 + u;
                gv[gate] = gparts[m * 33 + n] + gparts[(32 + m) * 33 + n]
                         + g1[((size_t)(t * 32 + m) * 256 + blk) * 32 + n];
            }
            float ig = sigm(gv[0]), fg = sigm(gv[1]), g2 = tanhf(gv[2]), og = sigm(gv[3]);
            c1 = fg * c1 + ig * g2;
            float hval = og * tanhf(c1);
            fsum += hval * ((t == 1) ? lw1 : (t == 2) ? lw2 : lw3);
            if (t < 3) store_h(h1_ws + (size_t)(t * 32 + m) * 2048 + blk * 8 + u, hval);
        }
        if (t < 3) {
            gbar_arrive(ws, 4 + t, blk);
            gbar_wait(ws, 4 + t, blk);
        }
    }

    // ---------- distributed final linear + sigmoid (no barrier) ----------
    if (tid < 256) {
        float v = fsum;
        v += __shfl_down(v, 4, 8);
        v += __shfl_down(v, 2, 8);
        v += __shfl_down(v, 1, 8);
        if (u == 0) {
            atomicAdd(facc + m, v);                       // agent-scope float atomic at L3
            asm volatile("s_waitcnt vmcnt(0)" ::: "memory");  // my add performed before count
            unsigned old = __hip_atomic_fetch_add(fcnt + m, 1u, __ATOMIC_RELAXED, __HIP_MEMORY_SCOPE_AGENT);
            if (old == (unsigned)(NBLK - 1)) {            // last contributor finalizes
                float s = __hip_atomic_load(facc + m, __ATOMIC_RELAXED, __HIP_MEMORY_SCOPE_AGENT);
                out[m] = 1.f / (1.f + expf(-(s + linb)));
            }
        }
    }
}

extern "C" void kernel_launch(void* const* d_in, const int* in_sizes, int n_in,
                              void* d_out, int out_size, void* d_ws, size_t ws_size,
                              hipStream_t stream) {
    const float* state  = (const float*)d_in[0];
    const float* action = (const float*)d_in[1];
    const float* conv_w = (const float*)d_in[2];
    const float* conv_b = (const float*)d_in[3];
    const float* w_ih0  = (const float*)d_in[4];
    const float* w_hh0  = (const float*)d_in[5];
    const float* b_ih0  = (const float*)d_in[6];
    const float* b_hh0  = (const float*)d_in[7];
    const float* w_ih1  = (const float*)d_in[8];
    const float* w_hh1  = (const float*)d_in[9];
    const float* b_ih1  = (const float*)d_in[10];
    const float* b_hh1  = (const float*)d_in[11];
    const float* lin_w  = (const float*)d_in[12];
    const float* lin_b  = (const float*)d_in[13];
    float* out = (float*)d_out;
    char*  ws  = (char*)d_ws;

    hipMemsetAsync(ws, 0, BAR_BYTES, stream);   // zero barriers + final accum/count

    // Plain launch: grid == 256 == #CUs, 152 KiB LDS forces 1 block/CU, so all
    // blocks are co-resident and the ws-based barrier is safe.
    hipLaunchKernelGGL(fused_lstm, dim3(NBLK), dim3(NTHR), LDS_TOTAL, stream,
                       state, action, conv_w, conv_b, w_ih0, w_hh0, b_ih0, b_hh0,
                       w_ih1, w_hh1, b_ih1, b_hh1, lin_w, lin_b, out, ws);
}